// Round 6
// baseline (1753.896 us; speedup 1.0000x reference)
//
#include <hip/hip_runtime.h>

#define B_SZ   65536
#define IN_SZ  256
#define H_SZ   512
#define K_SZ   768          // IN + H
#define BM     64           // rows per block; each block does ALL 1024 output cols
#define BK     64
#define LDK    72           // padded LDS K-stride (bf16 elems); 144 B rows, 16B aligned
#define NCHUNK (K_SZ / BK)  // 12
#define SLDN   516          // epilogue slab stride (floats): 2064 B row stride

typedef __attribute__((ext_vector_type(4))) float          f32x4;
typedef __attribute__((ext_vector_type(8))) __bf16         bf16x8;
typedef __attribute__((ext_vector_type(4))) unsigned short u16x4;

__device__ __forceinline__ unsigned short f2bf(float f) {
    unsigned u = __float_as_uint(f);
    u += 0x7FFFu + ((u >> 16) & 1u);      // round-to-nearest-even
    return (unsigned short)(u >> 16);
}

__device__ __forceinline__ float tanh_fast(float x) {
    x = fminf(fmaxf(x, -16.0f), 16.0f);
    float e = __expf(2.0f * x);
    return (e - 1.0f) / (e + 1.0f);
}

// Build Wt[1024][768] bf16, k-major: rows 0..511 = f-set cols, 512..1023 = c-set cols.
__global__ void prep_weights(const float* __restrict__ w_f, const float* __restrict__ w_c,
                             const float* __restrict__ r_f, const float* __restrict__ r_c,
                             unsigned short* __restrict__ wt) {
    int id = blockIdx.x * 256 + threadIdx.x;
    int n  = id / K_SZ;
    int k  = id - n * K_SZ;
    int col = n & (H_SZ - 1);
    float v;
    if (n < H_SZ) v = (k < IN_SZ) ? w_f[k * H_SZ + col] : r_f[(k - IN_SZ) * H_SZ + col];
    else          v = (k < IN_SZ) ? w_c[k * H_SZ + col] : r_c[(k - IN_SZ) * H_SZ + col];
    wt[(size_t)n * K_SZ + k] = f2bf(v);
}

// Round-6: R3 structure (fastest, 938 us, nt loads restored) with ONE change:
// the epilogue store stream is SCALAR dword, consecutive lanes -> consecutive
// dwords (256 B contiguous per wave store instruction).  A/B vs R3 isolates
// store WIDTH — the only write-path variable common to rounds 1-5 (dwordx4,
// WRITE=7.87x ideal ~= one 128 B line per 16 B store) and absent in round 0
// (scalar dword, WRITE=1.64x ideal). Store policy, pattern, epilogue
// structure, VGPR pressure, block count, and nt-loads are all falsified.
__launch_bounds__(512, 2)
__global__ void smgu_kernel(const float* __restrict__ x, const float* __restrict__ h_prev,
                            const float* __restrict__ c_prev, const float* __restrict__ n_prev,
                            const float* __restrict__ m_prev,
                            const float* __restrict__ b_f, const float* __restrict__ b_c,
                            const unsigned short* __restrict__ wt,
                            float* __restrict__ out) {
    // union: K-loop uses sA [2][BM][LDK] bf16 = 18432 B;
    //        epilogue uses 2 slabs of [16][SLDN] f32 = 66048 B
    __shared__ __align__(16) unsigned char smem[2 * 16 * SLDN * 4];
    unsigned short* sA    = (unsigned short*)smem;
    float*          slabF = (float*)smem;
    float*          slabC = slabF + 16 * SLDN;

    const int tid  = threadIdx.x;
    const int m0   = blockIdx.x * BM;
    const int lane = tid & 63;
    const int wave = tid >> 6;            // 0..7 -> H-col group
    const int n0   = wave * 64;
    const int fr   = lane & 15;
    const int fg   = (lane >> 4) * 8;     // k-octet offset
    const int g    = lane >> 4;

    f32x4 accF[4][4], accC[4][4];
#pragma unroll
    for (int i = 0; i < 4; ++i)
#pragma unroll
        for (int j = 0; j < 4; ++j) { accF[i][j] = (f32x4)0.0f; accC[i][j] = (f32x4)0.0f; }

    // staging map: 1024 float4 chunks (64 rows x 16), thread does chunks tid and tid+512
    const int r0s = tid >> 4;             // 0..31
    const int c4s = tid & 15;

    f32x4 pv0, pv1;
    auto load_chunk = [&](int kb) {
        const float* src; int ld, kl;
        if (kb < IN_SZ) { src = x;      ld = IN_SZ; kl = kb; }
        else            { src = h_prev; ld = H_SZ;  kl = kb - IN_SZ; }
        pv0 = __builtin_nontemporal_load(
            (const f32x4*)&src[(size_t)(m0 + r0s) * ld + kl + c4s * 4]);
        pv1 = __builtin_nontemporal_load(
            (const f32x4*)&src[(size_t)(m0 + 32 + r0s) * ld + kl + c4s * 4]);
    };
    auto write_chunk = [&](int buf) {
        u16x4 w0, w1;
        w0[0] = f2bf(pv0[0]); w0[1] = f2bf(pv0[1]); w0[2] = f2bf(pv0[2]); w0[3] = f2bf(pv0[3]);
        w1[0] = f2bf(pv1[0]); w1[1] = f2bf(pv1[1]); w1[2] = f2bf(pv1[2]); w1[3] = f2bf(pv1[3]);
        *(u16x4*)&sA[(buf * BM + r0s) * LDK + c4s * 4]      = w0;
        *(u16x4*)&sA[(buf * BM + 32 + r0s) * LDK + c4s * 4] = w1;
    };

    load_chunk(0);
    write_chunk(0);
    __syncthreads();

    for (int t = 0; t < NCHUNK; ++t) {
        const int cur = t & 1;
        if (t + 1 < NCHUNK) load_chunk((t + 1) * BK);   // HBM latency hides under MFMAs
        const unsigned short* sAc = &sA[cur * BM * LDK];
#pragma unroll
        for (int ks = 0; ks < BK; ks += 32) {
            bf16x8 af[4], bfx[4], bcx[4];
#pragma unroll
            for (int mi = 0; mi < 4; ++mi)
                af[mi] = *(const bf16x8*)&sAc[(mi * 16 + fr) * LDK + ks + fg];
            const int kk = t * BK + ks + fg;
#pragma unroll
            for (int ni = 0; ni < 4; ++ni) {
                const int nr = n0 + ni * 16 + fr;
                bfx[ni] = *(const bf16x8*)&wt[(size_t)nr * K_SZ + kk];            // L2 hit
                bcx[ni] = *(const bf16x8*)&wt[(size_t)(H_SZ + nr) * K_SZ + kk];   // L2 hit
            }
#pragma unroll
            for (int mi = 0; mi < 4; ++mi)
#pragma unroll
                for (int ni = 0; ni < 4; ++ni) {
                    accF[mi][ni] = __builtin_amdgcn_mfma_f32_16x16x32_bf16(af[mi], bfx[ni], accF[mi][ni], 0, 0, 0);
                    accC[mi][ni] = __builtin_amdgcn_mfma_f32_16x16x32_bf16(af[mi], bcx[ni], accC[mi][ni], 0, 0, 0);
                }
        }
        if (t + 1 < NCHUNK) write_chunk(cur ^ 1);
        __syncthreads();   // final iter: fences LDS before epilogue slab reuse
    }

    // ---- epilogue: block-linear via LDS slab exchange, SCALAR element pass.
    // MFMA C/D layout: col = ni*16 + (lane&15), row = (lane>>4)*4 + reg  [m89/m91]
    const size_t BH = (size_t)B_SZ * H_SZ;

#pragma unroll 1
    for (int mi = 0; mi < 4; ++mi) {
        // stage raw pre-activations for these 16 rows x 512 cols
#pragma unroll
        for (int ni = 0; ni < 4; ++ni)
#pragma unroll
            for (int r = 0; r < 4; ++r) {
                const int rl = g * 4 + r;
                const int cc = n0 + ni * 16 + fr;
                slabF[rl * SLDN + cc] = accF[mi][ni][r];
                slabC[rl * SLDN + cc] = accC[mi][ni][r];
            }
        __syncthreads();

        // linear pass: 16 rows x 512 cols = 8192 floats; 16 per thread.
        // e = tid + 512*k -> consecutive lanes write consecutive dwords:
        // each wave store instruction covers 256 B contiguous (round-0 shape).
#pragma unroll
        for (int k = 0; k < 16; ++k) {
            const int e   = tid + 512 * k;
            const int row = e >> 9;              // 0..15
            const int col = e & 511;
            const size_t idx = (size_t)(m0 + mi * 16 + row) * H_SZ + col;
            float pF = slabF[row * SLDN + col];
            float pC = slabC[row * SLDN + col];
            float cp = __builtin_nontemporal_load(&c_prev[idx]);
            float np = __builtin_nontemporal_load(&n_prev[idx]);
            float mp = __builtin_nontemporal_load(&m_prev[idx]);
            float preF = pF + b_f[col];
            float s    = preF + mp;
            float mt   = fmaxf(s, 0.0f);
            float ipv  = __expf(-mt);
            float fpv  = __expf(s - mt);
            float ct   = fpv * cp + ipv * tanh_fast(pC + b_c[col]);
            float ntv  = fpv * np + ipv;
            float htv  = tanh_fast(ct / fmaxf(ntv, 1e-8f));
            out[idx]          = htv;
            out[BH + idx]     = ct;
            out[2 * BH + idx] = ntv;
            out[3 * BH + idx] = mt;
        }
        __syncthreads();   // slabs reused next mi
    }
}

extern "C" void kernel_launch(void* const* d_in, const int* in_sizes, int n_in,
                              void* d_out, int out_size, void* d_ws, size_t ws_size,
                              hipStream_t stream) {
    const float* x      = (const float*)d_in[0];
    const float* h_prev = (const float*)d_in[1];
    const float* c_prev = (const float*)d_in[2];
    const float* n_prev = (const float*)d_in[3];
    const float* m_prev = (const float*)d_in[4];
    const float* w_f    = (const float*)d_in[5];
    const float* w_c    = (const float*)d_in[6];
    const float* r_f    = (const float*)d_in[7];
    const float* r_c    = (const float*)d_in[8];
    const float* b_f    = (const float*)d_in[9];
    const float* b_c    = (const float*)d_in[10];
    float* out = (float*)d_out;
    unsigned short* wt = (unsigned short*)d_ws;   // 1024*768*2 = 1.5 MiB

    prep_weights<<<(2 * H_SZ * K_SZ) / 256, 256, 0, stream>>>(w_f, w_c, r_f, r_c, wt);
    smgu_kernel<<<B_SZ / BM, 512, 0, stream>>>(
        x, h_prev, c_prev, n_prev, m_prev, b_f, b_c, wt, out);
}

// Round 7
// 1312.421 us; speedup vs baseline: 1.3364x; 1.3364x over previous
//
#include <hip/hip_runtime.h>

#define B_SZ   65536
#define IN_SZ  256
#define H_SZ   512
#define K_SZ   768          // IN + H
#define BM     128
#define BN     128
#define BK     64
#define LDK    72           // padded LDS K-stride (elems); 144 B rows -> 16B aligned, 2-way banks

typedef __attribute__((ext_vector_type(4))) float  f32x4;
typedef __attribute__((ext_vector_type(8))) __bf16 bf16x8;

__device__ __forceinline__ unsigned short f2bf(float f) {
    unsigned u = __float_as_uint(f);
    u += 0x7FFFu + ((u >> 16) & 1u);      // round-to-nearest-even
    return (unsigned short)(u >> 16);
}

__device__ __forceinline__ float tanh_fast(float x) {
    x = fminf(fmaxf(x, -16.0f), 16.0f);   // avoid inf/inf; tanh saturates to 1.0f well before 16
    float e = __expf(2.0f * x);
    return (e - 1.0f) / (e + 1.0f);
}

// Build Wt[1024][768] bf16, k-major ("B^T input"): rows 0..511 = f-set cols, 512..1023 = c-set cols.
__global__ void prep_weights(const float* __restrict__ w_f, const float* __restrict__ w_c,
                             const float* __restrict__ r_f, const float* __restrict__ r_c,
                             unsigned short* __restrict__ wt) {
    int id = blockIdx.x * 256 + threadIdx.x;      // 0 .. 1024*768-1
    int n  = id / K_SZ;
    int k  = id - n * K_SZ;
    int col = n & (H_SZ - 1);
    float v;
    if (n < H_SZ) v = (k < IN_SZ) ? w_f[k * H_SZ + col] : r_f[(k - IN_SZ) * H_SZ + col];
    else          v = (k < IN_SZ) ? w_c[k * H_SZ + col] : r_c[(k - IN_SZ) * H_SZ + col];
    wt[(size_t)n * K_SZ + k] = f2bf(v);
}

// Round-7: ROUND-0 CHAMPION (685 us) + ONE change: bijective XCD-aware block
// swizzle (T1). Rounds 1-6 established the R1+ full-H restructure is slower on
// the clock regardless of its write-counter profile (likely a gfx950 counter
// formula artifact; gfx94x fallback). Round 0's measured defect is FETCH =
// 985 MB vs 577 ideal: the 4 tile_n sharers of each A-panel (x,h rows) land on
// 4 different XCDs under round-robin dispatch, so private L2s can't dedup the
// re-reads. Swizzle bid = (hw%8)*256 + hw/8 puts all 4 sharers of a tile_m on
// the SAME XCD, dispatched adjacently -> A-panel fetched from HBM once/XCD,
// re-reads are L2 hits (wt 1.5 MB stays resident alongside in the 4 MB L2).
__launch_bounds__(256, 2)
__global__ void smgu_kernel(const float* __restrict__ x, const float* __restrict__ h_prev,
                            const float* __restrict__ c_prev, const float* __restrict__ n_prev,
                            const float* __restrict__ m_prev,
                            const float* __restrict__ b_f, const float* __restrict__ b_c,
                            const unsigned short* __restrict__ wt,
                            float* __restrict__ out) {
    __shared__ unsigned short sA[BM * LDK];
    __shared__ unsigned short sF[BN * LDK];
    __shared__ unsigned short sC[BN * LDK];

    const int tid    = threadIdx.x;
    // XCD swizzle: hw index d runs round-robin over 8 XCDs (d%8). Remap so XCD k
    // gets original bids [k*256, (k+1)*256): consecutive bids (the 4 tile_n
    // sharers of each tile_m) co-locate on one XCD, adjacent in dispatch order.
    const int bid    = (blockIdx.x & 7) * 256 + (blockIdx.x >> 3);   // 2048 % 8 == 0: bijective
    const int tile_m = bid >> 2;           // 512 row blocks
    const int tile_n = bid & 3;            // 4 col blocks over H
    const int m0 = tile_m * BM;
    const int n0 = tile_n * BN;            // H-column base

    const int lane = tid & 63;
    const int wave = tid >> 6;             // 4 waves, 2x2 grid of 64x64 sub-tiles
    const int wm = (wave >> 1) * 64;
    const int wn = (wave & 1) * 64;

    const int fr = lane & 15;              // fragment row/col within 16
    const int fg = (lane >> 4) * 8;        // k-octet offset

    f32x4 accF[4][4];
    f32x4 accC[4][4];
#pragma unroll
    for (int i = 0; i < 4; ++i)
#pragma unroll
        for (int j = 0; j < 4; ++j) { accF[i][j] = (f32x4)0.0f; accC[i][j] = (f32x4)0.0f; }

    for (int kb = 0; kb < K_SZ; kb += BK) {
        // ---- stage A (f32 -> bf16 in registers) : rows m0..m0+127, k kb..kb+63
        {
            const float* src; int ldsrc, kloc;
            if (kb < IN_SZ) { src = x;      ldsrc = IN_SZ; kloc = kb; }
            else            { src = h_prev; ldsrc = H_SZ;  kloc = kb - IN_SZ; }
#pragma unroll
            for (int j = 0; j < 8; ++j) {
                int idx = tid + 256 * j;          // 2048 float4 chunks
                int row = idx >> 4, c4 = idx & 15;
                const float4 v = *(const float4*)&src[(size_t)(m0 + row) * ldsrc + kloc + c4 * 4];
                ushort4 b;
                b.x = f2bf(v.x); b.y = f2bf(v.y); b.z = f2bf(v.z); b.w = f2bf(v.w);
                *(ushort4*)&sA[row * LDK + c4 * 4] = b;
            }
        }
        // ---- stage both weight tiles (already bf16 k-major in ws)
#pragma unroll
        for (int j = 0; j < 4; ++j) {
            int idx = tid + 256 * j;              // 1024 16B chunks per set
            int row = idx >> 3, c8 = idx & 7;
            uint4 vf = *(const uint4*)&wt[(size_t)(n0 + row) * K_SZ + kb + c8 * 8];
            *(uint4*)&sF[row * LDK + c8 * 8] = vf;
            uint4 vc = *(const uint4*)&wt[(size_t)(H_SZ + n0 + row) * K_SZ + kb + c8 * 8];
            *(uint4*)&sC[row * LDK + c8 * 8] = vc;
        }
        __syncthreads();

        // ---- MFMA over this K-chunk
#pragma unroll
        for (int ks = 0; ks < BK; ks += 32) {
            bf16x8 af[4], bf[4], bc[4];
#pragma unroll
            for (int mi = 0; mi < 4; ++mi)
                af[mi] = *(const bf16x8*)&sA[(wm + mi * 16 + fr) * LDK + ks + fg];
#pragma unroll
            for (int ni = 0; ni < 4; ++ni) {
                bf[ni] = *(const bf16x8*)&sF[(wn + ni * 16 + fr) * LDK + ks + fg];
                bc[ni] = *(const bf16x8*)&sC[(wn + ni * 16 + fr) * LDK + ks + fg];
            }
#pragma unroll
            for (int mi = 0; mi < 4; ++mi)
#pragma unroll
                for (int ni = 0; ni < 4; ++ni) {
                    accF[mi][ni] = __builtin_amdgcn_mfma_f32_16x16x32_bf16(af[mi], bf[ni], accF[mi][ni], 0, 0, 0);
                    accC[mi][ni] = __builtin_amdgcn_mfma_f32_16x16x32_bf16(af[mi], bc[ni], accC[mi][ni], 0, 0, 0);
                }
        }
        __syncthreads();
    }

    // ---- fused epilogue. C/D layout: col = lane&15, row = (lane>>4)*4 + reg  [m89/m91-verified]
    const size_t BH = (size_t)B_SZ * H_SZ;
#pragma unroll
    for (int ni = 0; ni < 4; ++ni) {
        int col = n0 + wn + ni * 16 + fr;
        float bfv = b_f[col], bcv = b_c[col];
#pragma unroll
        for (int mi = 0; mi < 4; ++mi) {
            int row0 = m0 + wm + mi * 16 + (lane >> 4) * 4;
#pragma unroll
            for (int r = 0; r < 4; ++r) {
                size_t idx = (size_t)(row0 + r) * H_SZ + col;
                float pre_f = accF[mi][ni][r] + bfv;
                float pre_c = accC[mi][ni][r] + bcv;
                float mp = m_prev[idx];
                float s  = pre_f + mp;
                float m_t = fmaxf(s, 0.0f);
                float ip  = __expf(-m_t);
                float fp  = __expf(s - m_t);
                float cp  = c_prev[idx];
                float np  = n_prev[idx];
                float c_t = fp * cp + ip * tanh_fast(pre_c);
                float n_t = fp * np + ip;
                float h_t = tanh_fast(c_t / fmaxf(n_t, 1e-8f));
                out[idx]          = h_t;
                out[BH + idx]     = c_t;
                out[2 * BH + idx] = n_t;
                out[3 * BH + idx] = m_t;
            }
        }
    }
}

extern "C" void kernel_launch(void* const* d_in, const int* in_sizes, int n_in,
                              void* d_out, int out_size, void* d_ws, size_t ws_size,
                              hipStream_t stream) {
    const float* x      = (const float*)d_in[0];
    const float* h_prev = (const float*)d_in[1];
    const float* c_prev = (const float*)d_in[2];
    const float* n_prev = (const float*)d_in[3];
    const float* m_prev = (const float*)d_in[4];
    const float* w_f    = (const float*)d_in[5];
    const float* w_c    = (const float*)d_in[6];
    const float* r_f    = (const float*)d_in[7];
    const float* r_c    = (const float*)d_in[8];
    const float* b_f    = (const float*)d_in[9];
    const float* b_c    = (const float*)d_in[10];
    float* out = (float*)d_out;
    unsigned short* wt = (unsigned short*)d_ws;   // 1024*768*2 = 1.5 MiB

    prep_weights<<<(2 * H_SZ * K_SZ) / 256, 256, 0, stream>>>(w_f, w_c, r_f, r_c, wt);
    smgu_kernel<<<(B_SZ / BM) * (H_SZ / BN), 256, 0, stream>>>(
        x, h_prev, c_prev, n_prev, m_prev, b_f, b_c, wt, out);
}

// Round 8
// 1172.218 us; speedup vs baseline: 1.4962x; 1.1196x over previous
//
#include <hip/hip_runtime.h>

#define B_SZ   65536
#define IN_SZ  256
#define H_SZ   512
#define K_SZ   768          // IN + H
#define BM     128
#define BN     128
#define BK     64
#define LDK    72           // padded LDS K-stride (elems); 144 B rows -> 16B aligned, 2-way banks
#define NCHUNK (K_SZ / BK)  // 12

typedef __attribute__((ext_vector_type(4))) float  f32x4;
typedef __attribute__((ext_vector_type(8))) __bf16 bf16x8;

__device__ __forceinline__ unsigned short f2bf(float f) {
    unsigned u = __float_as_uint(f);
    u += 0x7FFFu + ((u >> 16) & 1u);      // round-to-nearest-even
    return (unsigned short)(u >> 16);
}

__device__ __forceinline__ float tanh_fast(float x) {
    x = fminf(fmaxf(x, -16.0f), 16.0f);   // avoid inf/inf; tanh saturates well before 16
    float e = __expf(2.0f * x);
    return (e - 1.0f) / (e + 1.0f);
}

// Build Wt[1024][768] bf16, k-major ("B^T input"): rows 0..511 = f-set cols, 512..1023 = c-set cols.
__global__ void prep_weights(const float* __restrict__ w_f, const float* __restrict__ w_c,
                             const float* __restrict__ r_f, const float* __restrict__ r_c,
                             unsigned short* __restrict__ wt) {
    int id = blockIdx.x * 256 + threadIdx.x;      // 0 .. 1024*768-1
    int n  = id / K_SZ;
    int k  = id - n * K_SZ;
    int col = n & (H_SZ - 1);
    float v;
    if (n < H_SZ) v = (k < IN_SZ) ? w_f[k * H_SZ + col] : r_f[(k - IN_SZ) * H_SZ + col];
    else          v = (k < IN_SZ) ? w_c[k * H_SZ + col] : r_c[(k - IN_SZ) * H_SZ + col];
    wt[(size_t)n * K_SZ + k] = f2bf(v);
}

// Round-8: R7 champion (671 us) + register PREFETCH in the K-loop (T14 split).
// R7 showed the kernel is latency-bound, not traffic-bound (FETCH -285 MB ->
// dur -2%; achieved BW 2.33 TB/s matches Little's law at ~35% memory duty
// cycle). Fix: issue chunk t+1's global loads (A + both wt tiles) into regs
// right after the post-staging barrier, BEFORE the MFMA phase -> ~900 cyc HBM
// latency hides under 128 wave-MFMAs; vmcnt drain lands at the next LDS write.
// Also: epilogue loops reordered mi-outer/ni-inner so the two 64 B halves of
// each 128 B out-line are adjacent in the store stream (targets the 1.6x write
// amplification, 827 vs 512 MB ideal).
__launch_bounds__(256, 2)
__global__ void smgu_kernel(const float* __restrict__ x, const float* __restrict__ h_prev,
                            const float* __restrict__ c_prev, const float* __restrict__ n_prev,
                            const float* __restrict__ m_prev,
                            const float* __restrict__ b_f, const float* __restrict__ b_c,
                            const unsigned short* __restrict__ wt,
                            float* __restrict__ out) {
    __shared__ unsigned short sA[BM * LDK];
    __shared__ unsigned short sF[BN * LDK];
    __shared__ unsigned short sC[BN * LDK];

    const int tid    = threadIdx.x;
    // XCD swizzle (bijective: 2048 % 8 == 0): all 4 tile_n sharers of a tile_m
    // land on the same XCD, adjacent in dispatch order -> A re-reads are L2 hits.
    const int bid    = (blockIdx.x & 7) * 256 + (blockIdx.x >> 3);
    const int tile_m = bid >> 2;           // 512 row blocks
    const int tile_n = bid & 3;            // 4 col blocks over H
    const int m0 = tile_m * BM;
    const int n0 = tile_n * BN;            // H-column base

    const int lane = tid & 63;
    const int wave = tid >> 6;             // 4 waves, 2x2 grid of 64x64 sub-tiles
    const int wm = (wave >> 1) * 64;
    const int wn = (wave & 1) * 64;

    const int fr = lane & 15;              // fragment row/col within 16
    const int fg = (lane >> 4) * 8;        // k-octet offset

    f32x4 accF[4][4];
    f32x4 accC[4][4];
#pragma unroll
    for (int i = 0; i < 4; ++i)
#pragma unroll
        for (int j = 0; j < 4; ++j) { accF[i][j] = (f32x4)0.0f; accC[i][j] = (f32x4)0.0f; }

    // staging maps (constant per thread):
    const int r0a = tid >> 4;              // A: rows r0a + 16*j, 16B col chunk c4a
    const int c4a = tid & 15;
    const int r0w = tid >> 3;              // W: rows r0w + 32*j, 16B col chunk c8w
    const int c8w = tid & 7;

    f32x4 pA[8];
    uint4 pF[4], pC[4];

    auto load_tiles = [&](int kb) {
        const float* src; int ldsrc, kloc;
        if (kb < IN_SZ) { src = x;      ldsrc = IN_SZ; kloc = kb; }
        else            { src = h_prev; ldsrc = H_SZ;  kloc = kb - IN_SZ; }
#pragma unroll
        for (int j = 0; j < 8; ++j)
            pA[j] = *(const f32x4*)&src[(size_t)(m0 + r0a + 16 * j) * ldsrc + kloc + c4a * 4];
#pragma unroll
        for (int j = 0; j < 4; ++j) {
            pF[j] = *(const uint4*)&wt[(size_t)(n0 + r0w + 32 * j) * K_SZ + kb + c8w * 8];
            pC[j] = *(const uint4*)&wt[(size_t)(H_SZ + n0 + r0w + 32 * j) * K_SZ + kb + c8w * 8];
        }
    };
    auto store_tiles = [&]() {
#pragma unroll
        for (int j = 0; j < 8; ++j) {
            ushort4 b;
            b.x = f2bf(pA[j][0]); b.y = f2bf(pA[j][1]);
            b.z = f2bf(pA[j][2]); b.w = f2bf(pA[j][3]);
            *(ushort4*)&sA[(r0a + 16 * j) * LDK + c4a * 4] = b;
        }
#pragma unroll
        for (int j = 0; j < 4; ++j) {
            *(uint4*)&sF[(r0w + 32 * j) * LDK + c8w * 8] = pF[j];
            *(uint4*)&sC[(r0w + 32 * j) * LDK + c8w * 8] = pC[j];
        }
    };

    load_tiles(0);

    for (int t = 0; t < NCHUNK; ++t) {
        store_tiles();                         // waits on t's loads, fills LDS
        __syncthreads();
        if (t + 1 < NCHUNK) load_tiles((t + 1) * BK);   // in flight during MFMA

        // ---- MFMA over this K-chunk (LDS-resident)
#pragma unroll
        for (int ks = 0; ks < BK; ks += 32) {
            bf16x8 af[4], bf[4], bc[4];
#pragma unroll
            for (int mi = 0; mi < 4; ++mi)
                af[mi] = *(const bf16x8*)&sA[(wm + mi * 16 + fr) * LDK + ks + fg];
#pragma unroll
            for (int ni = 0; ni < 4; ++ni) {
                bf[ni] = *(const bf16x8*)&sF[(wn + ni * 16 + fr) * LDK + ks + fg];
                bc[ni] = *(const bf16x8*)&sC[(wn + ni * 16 + fr) * LDK + ks + fg];
            }
#pragma unroll
            for (int mi = 0; mi < 4; ++mi)
#pragma unroll
                for (int ni = 0; ni < 4; ++ni) {
                    accF[mi][ni] = __builtin_amdgcn_mfma_f32_16x16x32_bf16(af[mi], bf[ni], accF[mi][ni], 0, 0, 0);
                    accC[mi][ni] = __builtin_amdgcn_mfma_f32_16x16x32_bf16(af[mi], bc[ni], accC[mi][ni], 0, 0, 0);
                }
        }
        __syncthreads();                       // protect LDS before next store_tiles
    }

    // ---- fused epilogue. C/D layout: col = lane&15, row = (lane>>4)*4 + reg  [m89/m91-verified]
    // mi outer / ni inner: the two 64 B halves of each 128 B line (ni, ni+1)
    // are adjacent in the store stream -> L2 merges before eviction.
    const size_t BH = (size_t)B_SZ * H_SZ;
#pragma unroll
    for (int mi = 0; mi < 4; ++mi) {
        int row0 = m0 + wm + mi * 16 + (lane >> 4) * 4;
#pragma unroll
        for (int ni = 0; ni < 4; ++ni) {
            int col = n0 + wn + ni * 16 + fr;
            float bfv = b_f[col], bcv = b_c[col];
#pragma unroll
            for (int r = 0; r < 4; ++r) {
                size_t idx = (size_t)(row0 + r) * H_SZ + col;
                float pre_f = accF[mi][ni][r] + bfv;
                float pre_c = accC[mi][ni][r] + bcv;
                float mp = m_prev[idx];
                float s  = pre_f + mp;
                float m_t = fmaxf(s, 0.0f);
                float ip  = __expf(-m_t);
                float fp  = __expf(s - m_t);
                float cp  = c_prev[idx];
                float np  = n_prev[idx];
                float c_t = fp * cp + ip * tanh_fast(pre_c);
                float n_t = fp * np + ip;
                float h_t = tanh_fast(c_t / fmaxf(n_t, 1e-8f));
                out[idx]          = h_t;
                out[BH + idx]     = c_t;
                out[2 * BH + idx] = n_t;
                out[3 * BH + idx] = m_t;
            }
        }
    }
}

extern "C" void kernel_launch(void* const* d_in, const int* in_sizes, int n_in,
                              void* d_out, int out_size, void* d_ws, size_t ws_size,
                              hipStream_t stream) {
    const float* x      = (const float*)d_in[0];
    const float* h_prev = (const float*)d_in[1];
    const float* c_prev = (const float*)d_in[2];
    const float* n_prev = (const float*)d_in[3];
    const float* m_prev = (const float*)d_in[4];
    const float* w_f    = (const float*)d_in[5];
    const float* w_c    = (const float*)d_in[6];
    const float* r_f    = (const float*)d_in[7];
    const float* r_c    = (const float*)d_in[8];
    const float* b_f    = (const float*)d_in[9];
    const float* b_c    = (const float*)d_in[10];
    float* out = (float*)d_out;
    unsigned short* wt = (unsigned short*)d_ws;   // 1024*768*2 = 1.5 MiB

    prep_weights<<<(2 * H_SZ * K_SZ) / 256, 256, 0, stream>>>(w_f, w_c, r_f, r_c, wt);
    smgu_kernel<<<(B_SZ / BM) * (H_SZ / BN), 256, 0, stream>>>(
        x, h_prev, c_prev, n_prev, m_prev, b_f, b_c, wt, out);
}